// Round 1
// baseline (790.279 us; speedup 1.0000x reference)
//
#include <hip/hip_runtime.h>
#include <hip/hip_bf16.h>

#define B_  4
#define T_  256
#define U_  64
#define D_  512
#define INNER_ 512
#define VOCAB_ 2048

// ---------------- types ----------------
typedef __attribute__((ext_vector_type(8))) short short8;   // 8 bf16 (4 VGPRs)
typedef __attribute__((ext_vector_type(4))) float f32x4;

// ---------------- pass 1: projections (fp32) ----------------
// encP[bt][c] = sum_k enc[bt][k] * W1[k][c]
// decPb[bu][c] = sum_k dec[bu][k] * W1[512+k][c] + b1[c]
__global__ __launch_bounds__(256) void proj_kernel(
    const float* __restrict__ enc, const float* __restrict__ dec,
    const float* __restrict__ W1, const float* __restrict__ b1,
    float* __restrict__ encP, float* __restrict__ decPb) {
  int ct = blockIdx.x;   // 0..3 col tiles of 128
  int rt = blockIdx.y;   // 0..79 row tiles of 16 (64 enc + 16 dec)
  const float* src; float* dst; int kOff; int addB1; int rowBase;
  if (rt < 64) { src = enc; dst = encP; kOff = 0; addB1 = 0; rowBase = rt * 16; }
  else { src = dec; dst = decPb; kOff = D_; addB1 = 1; rowBase = (rt - 64) * 16; }

  __shared__ float As[16][D_];  // 32 KiB
  int tid = threadIdx.x;
  const float4* s4 = (const float4*)(src + (size_t)rowBase * D_);
  float4* a4 = (float4*)(&As[0][0]);
#pragma unroll
  for (int i = 0; i < 8; i++) a4[tid + 256 * i] = s4[tid + 256 * i];
  __syncthreads();

  int colQ = (tid & 31) * 4;        // 4 consecutive cols within 128-tile
  int col = ct * 128 + colQ;
  int r0 = (tid >> 5) * 2;          // 2 rows
  float a00=0,a01=0,a02=0,a03=0, a10=0,a11=0,a12=0,a13=0;
  const float* Wp = W1 + (size_t)kOff * INNER_ + col;
#pragma unroll 4
  for (int k = 0; k < D_; k++) {
    float4 w = *(const float4*)(Wp + (size_t)k * INNER_);
    float e0 = As[r0][k], e1 = As[r0 + 1][k];
    a00 += e0 * w.x; a01 += e0 * w.y; a02 += e0 * w.z; a03 += e0 * w.w;
    a10 += e1 * w.x; a11 += e1 * w.y; a12 += e1 * w.z; a13 += e1 * w.w;
  }
  float4 bb = {0,0,0,0};
  if (addB1) bb = *(const float4*)(b1 + col);
  float4 o0 = {a00 + bb.x, a01 + bb.y, a02 + bb.z, a03 + bb.w};
  float4 o1 = {a10 + bb.x, a11 + bb.y, a12 + bb.z, a13 + bb.w};
  *(float4*)(dst + (size_t)(rowBase + r0) * INNER_ + col) = o0;
  *(float4*)(dst + (size_t)(rowBase + r0 + 1) * INNER_ + col) = o1;
}

// ---------------- pass 1b: W2 (512x2048 f32) -> W2T (2048x512 bf16) ----------------
__global__ __launch_bounds__(256) void w2t_kernel(
    const float* __restrict__ W2, __hip_bfloat16* __restrict__ W2T) {
  __shared__ float tile[32][33];
  int vBase = blockIdx.x * 32;  // 64
  int kBase = blockIdx.y * 32;  // 16
  int tx = threadIdx.x & 31, ty = threadIdx.x >> 5;  // 32 x 8
#pragma unroll
  for (int i = 0; i < 32; i += 8)
    tile[ty + i][tx] = W2[(size_t)(kBase + ty + i) * VOCAB_ + vBase + tx];
  __syncthreads();
#pragma unroll
  for (int i = 0; i < 32; i += 8)
    W2T[(size_t)(vBase + ty + i) * INNER_ + kBase + tx] = __float2bfloat16(tile[tx][ty + i]);
}

// ---------------- pass 2: hidden H[r][k] = tanh(encP[bt][k] + decPb[b*64+u][k]) ----------------
__global__ __launch_bounds__(256) void hidden_kernel(
    const float* __restrict__ encP, const float* __restrict__ decPb,
    __hip_bfloat16* __restrict__ H) {
  int gid = blockIdx.x * 256 + threadIdx.x;  // 4,194,304 total
  int k0 = (gid & 63) * 8;
  int r = gid >> 6;            // row in [0, 65536)
  int u = r & 63;
  int bt = r >> 6;             // b*T + t
  int b = bt >> 8;             // T = 256
  const float4* e = (const float4*)(encP + (size_t)bt * 512 + k0);
  const float4* dv = (const float4*)(decPb + (size_t)(b * 64 + u) * 512 + k0);
  float4 e0 = e[0], e1 = e[1];
  float4 d0 = dv[0], d1 = dv[1];
  union { __hip_bfloat16 h[8]; uint4 v; } p;
  p.h[0] = __float2bfloat16(tanhf(e0.x + d0.x));
  p.h[1] = __float2bfloat16(tanhf(e0.y + d0.y));
  p.h[2] = __float2bfloat16(tanhf(e0.z + d0.z));
  p.h[3] = __float2bfloat16(tanhf(e0.w + d0.w));
  p.h[4] = __float2bfloat16(tanhf(e1.x + d1.x));
  p.h[5] = __float2bfloat16(tanhf(e1.y + d1.y));
  p.h[6] = __float2bfloat16(tanhf(e1.z + d1.z));
  p.h[7] = __float2bfloat16(tanhf(e1.w + d1.w));
  *(uint4*)((__hip_bfloat16*)H + (size_t)r * 512 + k0) = p.v;
}

// ---------------- pass 3: main GEMM: out = H(65536x512) * W2T^T + b2 ----------------
__device__ inline void gload_lds16(const void* g, void* l) {
  __builtin_amdgcn_global_load_lds(
      (const __attribute__((address_space(1))) unsigned int*)g,
      (__attribute__((address_space(3))) unsigned int*)l, 16, 0, 0);
}

__global__ __launch_bounds__(256) void joint_gemm(
    const __hip_bfloat16* __restrict__ H, const __hip_bfloat16* __restrict__ W2T,
    const float* __restrict__ b2, float* __restrict__ out) {
  __shared__ __hip_bfloat16 As[128 * 64];  // [m][k], 16 KiB
  __shared__ __hip_bfloat16 Bs[128 * 64];  // [n][k], 16 KiB
  int ct = blockIdx.x;  // 0..15
  int rt = blockIdx.y;  // 0..511
  int tid = threadIdx.x;
  int wave = tid >> 6, lane = tid & 63;
  int wm = wave & 1, wn = wave >> 1;
  int rowBase = rt * 128, colBase = ct * 128;

  f32x4 acc[4][4];
#pragma unroll
  for (int ni = 0; ni < 4; ni++) {
    float bval = b2[colBase + wn * 64 + ni * 16 + (lane & 15)];
#pragma unroll
    for (int mi = 0; mi < 4; mi++) acc[mi][ni] = (f32x4){bval, bval, bval, bval};
  }

  int lrow = lane >> 3;        // 0..7 row within 8-row chunk
  int lk = (lane & 7) * 8;     // element offset within 64-wide k
  const __hip_bfloat16* Ag = H + (size_t)rowBase * 512;
  const __hip_bfloat16* Bg = W2T + (size_t)colBase * 512;

  for (int kt = 0; kt < 8; kt++) {
    int kOff = kt * 64;
    __syncthreads();
#pragma unroll
    for (int rnd = 0; rnd < 4; rnd++) {
      int rbase = wave * 8 + rnd * 32;
      gload_lds16(Ag + (size_t)(rbase + lrow) * 512 + kOff + lk, &As[rbase * 64]);
      gload_lds16(Bg + (size_t)(rbase + lrow) * 512 + kOff + lk, &Bs[rbase * 64]);
    }
    __syncthreads();
#pragma unroll
    for (int ks = 0; ks < 2; ks++) {
      short8 a[4], b[4];
      int kk = ks * 32 + (lane >> 4) * 8;
#pragma unroll
      for (int mi = 0; mi < 4; mi++)
        a[mi] = *(const short8*)&As[(wm * 64 + mi * 16 + (lane & 15)) * 64 + kk];
#pragma unroll
      for (int ni = 0; ni < 4; ni++)
        b[ni] = *(const short8*)&Bs[(wn * 64 + ni * 16 + (lane & 15)) * 64 + kk];
#pragma unroll
      for (int mi = 0; mi < 4; mi++)
#pragma unroll
        for (int ni = 0; ni < 4; ni++)
          acc[mi][ni] = __builtin_amdgcn_mfma_f32_16x16x32_bf16(a[mi], b[ni], acc[mi][ni], 0, 0, 0);
    }
  }

  // epilogue: C row = (lane>>4)*4 + j, col = lane&15
#pragma unroll
  for (int mi = 0; mi < 4; mi++) {
    int row = rowBase + wm * 64 + mi * 16 + ((lane >> 4) << 2);
#pragma unroll
    for (int ni = 0; ni < 4; ni++) {
      int col = colBase + wn * 64 + ni * 16 + (lane & 15);
#pragma unroll
      for (int j = 0; j < 4; j++)
        out[(size_t)(row + j) * VOCAB_ + col] = acc[mi][ni][j];
    }
  }
}

extern "C" void kernel_launch(void* const* d_in, const int* in_sizes, int n_in,
                              void* d_out, int out_size, void* d_ws, size_t ws_size,
                              hipStream_t stream) {
  const float* enc = (const float*)d_in[0];
  const float* dec = (const float*)d_in[1];
  const float* W1  = (const float*)d_in[2];
  const float* b1  = (const float*)d_in[3];
  const float* W2  = (const float*)d_in[4];
  const float* b2  = (const float*)d_in[5];
  float* out = (float*)d_out;

  char* ws = (char*)d_ws;
  float* encP  = (float*)ws;                                   // 1024*512*4 = 2 MiB
  float* decPb = (float*)(ws + (2u << 20));                    // 256*512*4 = 512 KiB
  __hip_bfloat16* W2T = (__hip_bfloat16*)(ws + (2u << 20) + (512u << 10));          // 2 MiB
  __hip_bfloat16* H   = (__hip_bfloat16*)(ws + (2u << 20) + (512u << 10) + (2u << 20)); // 64 MiB

  proj_kernel<<<dim3(4, 80), 256, 0, stream>>>(enc, dec, W1, b1, encP, decPb);
  w2t_kernel<<<dim3(64, 16), 256, 0, stream>>>(W2, W2T);
  hidden_kernel<<<16384, 256, 0, stream>>>(encP, decPb, H);
  joint_gemm<<<dim3(16, 512), 256, 0, stream>>>(H, W2T, b2, out);
}